// Round 2
// baseline (341.026 us; speedup 1.0000x reference)
//
#include <hip/hip_runtime.h>
#include <hip/hip_bf16.h>

#define NQ 65536
#define DIM 512
#define HID 256
#define NWAY 5
#define NKPTS 17

typedef short bf16x8 __attribute__((ext_vector_type(8)));
typedef float f32x4 __attribute__((ext_vector_type(4)));
typedef _Float16 half8 __attribute__((ext_vector_type(8)));

static __device__ __forceinline__ unsigned short f2bf(float f) {
    unsigned int x = __float_as_uint(f);
    unsigned int r = (x + 0x7fffu + ((x >> 16) & 1u)) >> 16;
    return (unsigned short)r;
}

static __device__ __forceinline__ void async16(void* l, const void* g) {
    __builtin_amdgcn_global_load_lds(
        (const __attribute__((address_space(1))) unsigned int*)g,
        (__attribute__((address_space(3))) unsigned int*)l, 16, 0, 0);
}

// ---------------- support layer 1: ws_h1 = relu(sf@W1+b1), coalesced over columns ----------
__global__ __launch_bounds__(256) void k_sup(const float* __restrict__ sf,
                                             const float* __restrict__ W1, const float* __restrict__ b1,
                                             float* __restrict__ ws_h1) {
    __shared__ float sfl[512];
    __shared__ float red[4][64];
    int bx = blockIdx.x;
    int s = bx >> 3, cb = bx & 7;
    int t = threadIdx.x;
    if (t < 128) ((float4*)sfl)[t] = ((const float4*)(sf + s * DIM))[t];
    __syncthreads();
    int c = cb * 64 + (t & 63);
    int qd = t >> 6;                 // k-quarter 0..3 (wave-uniform)
    const float* Wp = W1 + (size_t)qd * 128 * DIM + c;
    float acc = 0.0f;
    #pragma unroll 4
    for (int kk = 0; kk < 128; kk++)
        acc += sfl[qd * 128 + kk] * Wp[(size_t)kk * DIM];
    red[qd][t & 63] = acc;
    __syncthreads();
    if (t < 64) {
        float h = red[0][t] + red[1][t] + red[2][t] + red[3][t] + b1[cb * 64 + t];
        ws_h1[s * DIM + cb * 64 + t] = fmaxf(h, 0.0f);
    }
}

// ---------------- k_mid2: prototypes (mean then W2, coalesced) + [Wo1|Wc1] transpose->bf16 ----
__global__ __launch_bounds__(256) void k_mid2(const float* __restrict__ ws_h1,
                                              const float* __restrict__ W2, const float* __restrict__ b2,
                                              const float* __restrict__ Wo1, const float* __restrict__ Wc1,
                                              float* __restrict__ ws_proto, unsigned short* __restrict__ wb) {
    int bx = blockIdx.x;
    int t = threadIdx.x;
    if (bx < 40) {
        __shared__ float ml[512];
        __shared__ float red[4][64];
        int w = bx >> 3, cb = bx & 7;
        for (int i = t; i < 512; i += 256) {
            float sum = 0.0f;
            #pragma unroll
            for (int s5 = 0; s5 < 5; s5++) sum += ws_h1[(w * 5 + s5) * DIM + i];
            ml[i] = sum * 0.2f;
        }
        __syncthreads();
        int c = cb * 64 + (t & 63);
        int qd = t >> 6;
        const float* Wp = W2 + (size_t)qd * 128 * DIM + c;
        float acc = 0.0f;
        #pragma unroll 4
        for (int kk = 0; kk < 128; kk++)
            acc += ml[qd * 128 + kk] * Wp[(size_t)kk * DIM];
        red[qd][t & 63] = acc;
        __syncthreads();
        if (t < 64)
            ws_proto[w * DIM + cb * 64 + t] =
                red[0][t] + red[1][t] + red[2][t] + red[3][t] + b2[cb * 64 + t];
    } else {
        __shared__ unsigned short T[64][72];
        int tb = bx - 40;                    // 0..63
        const float* src = (tb < 32) ? Wo1 : Wc1;
        int cofs = (tb < 32) ? 0 : 256;
        int tt = tb & 31;
        int kt = tt >> 2;                    // k-tile 0..7
        int ct = tt & 3;                     // c-tile 0..3
        int i = t >> 2;                      // k row within tile 0..63
        int qd = t & 3;
        const float* rp = src + (size_t)(kt * 64 + i) * HID + ct * 64 + qd * 16;
        #pragma unroll
        for (int v = 0; v < 4; v++) {
            float4 x = *(const float4*)(rp + v * 4);
            T[qd * 16 + v * 4 + 0][i] = f2bf(x.x);
            T[qd * 16 + v * 4 + 1][i] = f2bf(x.y);
            T[qd * 16 + v * 4 + 2][i] = f2bf(x.z);
            T[qd * 16 + v * 4 + 3][i] = f2bf(x.w);
        }
        __syncthreads();
        int j = t >> 2;                      // c within tile
        int part = t & 3;
        uint4 o0 = *(const uint4*)&T[j][part * 16];
        uint4 o1 = *(const uint4*)&T[j][part * 16 + 8];
        unsigned short* dst = wb + (size_t)(cofs + ct * 64 + j) * DIM + kt * 64 + part * 16;
        *(uint4*)dst = o0;
        *(uint4*)(dst + 8) = o1;
    }
}

// ---------------- prepass: qf -> bf16 + f32 distances/argmin, ILP-batched reductions --------
// Wave handles 8 queries IN PARALLEL: all 16 global loads issued up front, 48 independent
// partial accumulators, one batched 6-round butterfly (48-wide ILP), predicated finalize.
__global__ __launch_bounds__(256) void k_prep(const float* __restrict__ qf,
                                              const float* __restrict__ ws_proto,
                                              const float* __restrict__ temp_p,
                                              unsigned short* __restrict__ qbf,
                                              float* __restrict__ out_dist, float* __restrict__ out_class,
                                              float* __restrict__ out_proto) {
    __shared__ float dlds[32 * NWAY];
    int bx = blockIdx.x, t = threadIdx.x;
    int wv = t >> 6, lane = t & 63;

    // out_proto broadcast (spread over blocks 0..84)
    if (bx < NWAY * NKPTS && t < 128) {
        f32x4 v = *(const f32x4*)(ws_proto + (bx / NKPTS) * DIM + t * 4);
        *(f32x4*)(out_proto + (size_t)bx * DIM + t * 4) = v;
    }

    float p[NWAY][8];
    float pn[NWAY];
    {
        float pp[NWAY];
        #pragma unroll
        for (int w = 0; w < NWAY; w++) {
            f32x4 a = *(const f32x4*)(ws_proto + w * DIM + lane * 8);
            f32x4 b = *(const f32x4*)(ws_proto + w * DIM + lane * 8 + 4);
            p[w][0] = a[0]; p[w][1] = a[1]; p[w][2] = a[2]; p[w][3] = a[3];
            p[w][4] = b[0]; p[w][5] = b[1]; p[w][6] = b[2]; p[w][7] = b[3];
            float s = 0.0f;
            #pragma unroll
            for (int j = 0; j < 8; j++) s += p[w][j] * p[w][j];
            pp[w] = s;
        }
        #pragma unroll
        for (int off = 32; off > 0; off >>= 1) {
            #pragma unroll
            for (int w = 0; w < NWAY; w++) pp[w] += __shfl_xor(pp[w], off, 64);
        }
        #pragma unroll
        for (int w = 0; w < NWAY; w++) pn[w] = sqrtf(pp[w]);
    }
    float invt = 1.0f / temp_p[0];

    int qbase = bx * 32 + wv * 8;
    const float* qp = qf + (size_t)qbase * DIM + lane * 8;
    unsigned short* qb = qbf + (size_t)qbase * DIM + lane * 8;

    float dq[8][NWAY + 1];
    #pragma unroll
    for (int qi = 0; qi < 8; qi++) {
        float4 v0 = *(const float4*)(qp + qi * DIM);
        float4 v1 = *(const float4*)(qp + qi * DIM + 4);
        unsigned int r0 = f2bf(v0.x) | ((unsigned int)f2bf(v0.y) << 16);
        unsigned int r1 = f2bf(v0.z) | ((unsigned int)f2bf(v0.w) << 16);
        unsigned int r2 = f2bf(v1.x) | ((unsigned int)f2bf(v1.y) << 16);
        unsigned int r3 = f2bf(v1.z) | ((unsigned int)f2bf(v1.w) << 16);
        *(uint4*)(qb + qi * DIM) = make_uint4(r0, r1, r2, r3);
        float av[8] = {v0.x, v0.y, v0.z, v0.w, v1.x, v1.y, v1.z, v1.w};
        #pragma unroll
        for (int w = 0; w < NWAY; w++) {
            float s = 0.0f;
            #pragma unroll
            for (int j = 0; j < 8; j++) s += av[j] * p[w][j];
            dq[qi][w] = s;
        }
        float s = 0.0f;
        #pragma unroll
        for (int j = 0; j < 8; j++) s += av[j] * av[j];
        dq[qi][NWAY] = s;
    }
    // one batched butterfly: 6 rounds x 48 independent values
    #pragma unroll
    for (int off = 32; off > 0; off >>= 1) {
        #pragma unroll
        for (int qi = 0; qi < 8; qi++) {
            #pragma unroll
            for (int j = 0; j < NWAY + 1; j++)
                dq[qi][j] += __shfl_xor(dq[qi][j], off, 64);
        }
    }
    // finalize: lane qi handles query qi (compile-time indices, predicated)
    if (lane < 8) {
        #pragma unroll
        for (int qi = 0; qi < 8; qi++) {
            if (lane == qi) {
                float qn = sqrtf(dq[qi][NWAY]);
                float mv = 1e30f; int ami = 0;
                #pragma unroll
                for (int w = 0; w < NWAY; w++) {
                    float den = fmaxf(qn * pn[w], 1e-8f);
                    float dd = (1.0f - dq[qi][w] / den) * invt;
                    dlds[(wv * 8 + qi) * NWAY + w] = dd;
                    if (dd < mv) { mv = dd; ami = w; }
                }
                out_class[qbase + qi] = (float)ami;
            }
        }
    }
    __syncthreads();
    int Q0 = bx * 32;
    for (int i = t; i < 32 * NWAY * NKPTS; i += 256) {
        int q2 = i / (NWAY * NKPTS);
        int rem = i - q2 * (NWAY * NKPTS);
        out_dist[(size_t)(Q0 + q2) * (NWAY * NKPTS) + rem] = dlds[q2 * NWAY + rem / NKPTS];
    }
}

// ---------------- unified MFMA GEMM: 128x512 tile (both heads), BK=32, A read ONCE ----------
// 512 thr / 8 waves (2Mx4N, wave=64x128), global_load_lds + XOR swizzle, double-buffered,
// one barrier per K-step. grid = 512 mtiles. Epilogue: offset head then conf head.
__global__ __launch_bounds__(512) void k_gemm(const unsigned short* __restrict__ qbf,
                                              const unsigned short* __restrict__ wb,
                                              const float* __restrict__ bo1, const float* __restrict__ Wo2,
                                              const float* __restrict__ bo2,
                                              const float* __restrict__ bc1, const float* __restrict__ Wc2,
                                              const float* __restrict__ bc2,
                                              const float* __restrict__ ic,
                                              float* __restrict__ out_kp, float* __restrict__ out_conf) {
    __shared__ __align__(16) char smem[81920];
    char* Abase = smem;                      // [2][128 rows][32 k] bf16 = 2 x 8 KB
    char* Bbase = smem + 16384;              // [2][512 cols][32 k] bf16 = 2 x 32 KB

    int mb = blockIdx.x;
    int t = threadIdx.x;
    int wv = t >> 6, lane = t & 63;
    int wr = wv >> 2, wc = wv & 3;
    int r = lane & 15, hq = lane >> 4;

    // staging: 1KB chunk = 16 rows x 64B; k-slot pre-swizzled in the GLOBAL src (rule 21)
    int srow = lane >> 2;                    // row within 16-row chunk
    int sg = (lane & 3) ^ (srow & 3);        // inverse-swizzled 16B k-slot
    const unsigned short* Ag = qbf + ((size_t)mb * 128 + wv * 16 + srow) * DIM + sg * 8;
    const unsigned short* Bg = wb + ((size_t)wv * 64 + srow) * DIM + sg * 8;

    f32x4 acc[4][8];
    #pragma unroll
    for (int i2 = 0; i2 < 4; i2++)
        #pragma unroll
        for (int j2 = 0; j2 < 8; j2++) { f32x4 z = {0.0f, 0.0f, 0.0f, 0.0f}; acc[i2][j2] = z; }

    // prologue: stage tile 0 into parity 0
    async16(Abase + wv * 1024, Ag);
    #pragma unroll
    for (int i = 0; i < 4; i++)
        async16(Bbase + wv * 4096 + i * 1024, Bg + (size_t)i * 16 * DIM);
    __syncthreads();

    for (int it = 0; it < 16; it++) {
        int par = it & 1;
        if (it < 15) {                       // prefetch next K-slice into other parity
            int ko = (it + 1) * 32;
            int np = par ^ 1;
            async16(Abase + np * 8192 + wv * 1024, Ag + ko);
            #pragma unroll
            for (int i = 0; i < 4; i++)
                async16(Bbase + np * 32768 + wv * 4096 + i * 1024, Bg + (size_t)i * 16 * DIM + ko);
        }
        const unsigned short* Ap = (const unsigned short*)(Abase + par * 8192);
        const unsigned short* Bp = (const unsigned short*)(Bbase + par * 32768);
        int sl = (hq ^ (r & 3)) * 8;         // swizzled 8-elem k-slot on the read side
        bf16x8 af[4], bfr[8];
        #pragma unroll
        for (int mt = 0; mt < 4; mt++) {
            int m = wr * 64 + mt * 16 + r;
            af[mt] = *(const bf16x8*)(Ap + m * 32 + sl);
        }
        #pragma unroll
        for (int nt = 0; nt < 8; nt++) {
            int c = wc * 128 + nt * 16 + r;
            bfr[nt] = *(const bf16x8*)(Bp + c * 32 + sl);
        }
        #pragma unroll
        for (int mt = 0; mt < 4; mt++)
            #pragma unroll
            for (int nt = 0; nt < 8; nt++)
                acc[mt][nt] = __builtin_amdgcn_mfma_f32_16x16x32_bf16(af[mt], bfr[nt], acc[mt][nt], 0, 0, 0);
        __syncthreads();
    }

    // ---- epilogue: two passes over the h tile (offset cols 0..255, conf cols 256..511) ----
    _Float16* hl = (_Float16*)smem;          // [128][264] f16 = 67584 B
    float* redf = (float*)(smem + 67584);    // partial sums, 4 KB

    // phase 1: offset-head h from waves wc<2
    if (wc < 2) {
        #pragma unroll
        for (int nt = 0; nt < 8; nt++) {
            int cl = wc * 128 + nt * 16 + r;             // 0..255
            float bv = bo1[cl];
            #pragma unroll
            for (int mt = 0; mt < 4; mt++)
                #pragma unroll
                for (int rg = 0; rg < 4; rg++) {
                    int ml = wr * 64 + mt * 16 + hq * 4 + rg;
                    hl[ml * 264 + cl] = (_Float16)fmaxf(acc[mt][nt][rg] + bv, 0.0f);
                }
        }
    }
    __syncthreads();
    {
        int q = t & 127, qt = t >> 7;
        float ox = 0.0f, oy = 0.0f;
        #pragma unroll 2
        for (int j0 = 0; j0 < 64; j0 += 8) {
            half8 hv = *(const half8*)(hl + q * 264 + qt * 64 + j0);
            #pragma unroll
            for (int j = 0; j < 8; j++) {
                float2 w2 = *(const float2*)(Wo2 + (qt * 64 + j0 + j) * 2);
                float hf = (float)hv[j];
                ox += hf * w2.x;
                oy += hf * w2.y;
            }
        }
        redf[(qt * 128 + q) * 2] = ox;
        redf[(qt * 128 + q) * 2 + 1] = oy;
    }
    __syncthreads();
    // offset finalize (waves 0,1) runs concurrently with conf h-write (waves wc>=2): disjoint LDS
    if (t < 128) {
        float sx = bo2[0], sy = bo2[1];
        #pragma unroll
        for (int k2 = 0; k2 < 4; k2++) {
            sx += redf[(k2 * 128 + t) * 2];
            sy += redf[(k2 * 128 + t) * 2 + 1];
        }
        size_t Q = (size_t)mb * 128 + t;
        float2 icv = *(const float2*)(ic + Q * 2);
        float gx = icv.x / (1.0f + __expf(-sx));
        float gy = icv.y / (1.0f + __expf(-sy));
        float2 g2 = make_float2(gx, gy);
        float2* dst = (float2*)(out_kp + Q * 34);
        #pragma unroll
        for (int k2 = 0; k2 < 17; k2++) dst[k2] = g2;
    }
    if (wc >= 2) {
        #pragma unroll
        for (int nt = 0; nt < 8; nt++) {
            int cl = (wc - 2) * 128 + nt * 16 + r;       // conf col 0..255
            float bv = bc1[cl];
            #pragma unroll
            for (int mt = 0; mt < 4; mt++)
                #pragma unroll
                for (int rg = 0; rg < 4; rg++) {
                    int ml = wr * 64 + mt * 16 + hq * 4 + rg;
                    hl[ml * 264 + cl] = (_Float16)fmaxf(acc[mt][nt][rg] + bv, 0.0f);
                }
        }
    }
    __syncthreads();
    {
        int q = t & 127, qt = t >> 7;
        float cs = 0.0f;
        #pragma unroll 2
        for (int j0 = 0; j0 < 64; j0 += 8) {
            half8 hv = *(const half8*)(hl + q * 264 + qt * 64 + j0);
            #pragma unroll
            for (int j = 0; j < 8; j++)
                cs += (float)hv[j] * Wc2[qt * 64 + j0 + j];
        }
        redf[qt * 128 + q] = cs;
    }
    __syncthreads();
    if (t < 128) {
        float s = bc2[0] + redf[t] + redf[128 + t] + redf[256 + t] + redf[384 + t];
        float sg2 = 1.0f / (1.0f + __expf(-s));
        size_t Q = (size_t)mb * 128 + t;
        float* dst = out_conf + Q * 17;
        #pragma unroll
        for (int k2 = 0; k2 < 17; k2++) dst[k2] = sg2;
    }
}

extern "C" void kernel_launch(void* const* d_in, const int* in_sizes, int n_in,
                              void* d_out, int out_size, void* d_ws, size_t ws_size,
                              hipStream_t stream) {
    const float* sf = (const float*)d_in[0];
    const float* qf = (const float*)d_in[2];
    const float* ic = (const float*)d_in[3];
    const float* W1 = (const float*)d_in[4];
    const float* b1 = (const float*)d_in[5];
    const float* W2 = (const float*)d_in[6];
    const float* b2 = (const float*)d_in[7];
    const float* Wo1 = (const float*)d_in[8];
    const float* bo1 = (const float*)d_in[9];
    const float* Wo2 = (const float*)d_in[10];
    const float* bo2 = (const float*)d_in[11];
    const float* Wc1 = (const float*)d_in[12];
    const float* bc1 = (const float*)d_in[13];
    const float* Wc2 = (const float*)d_in[14];
    const float* bc2 = (const float*)d_in[15];
    const float* temp = (const float*)d_in[16];

    float* out = (float*)d_out;
    float* out_kp = out;                   // 65536*17*2
    float* out_conf = out + 2228224;       // 65536*17
    float* out_dist = out + 3342336;       // 65536*5*17
    float* out_class = out + 8912896;      // 65536
    float* out_proto = out + 8978432;      // 5*17*512

    char* ws = (char*)d_ws;
    float* ws_h1 = (float*)ws;                               // 25*512 f32
    float* ws_proto = (float*)(ws + 51200);                  // 5*512 f32
    unsigned short* ws_wb = (unsigned short*)(ws + 65536);   // 512*512 bf16 (transposed [Wo1|Wc1])
    unsigned short* ws_qbf = (unsigned short*)(ws + 1048576);// 65536*512 bf16 query features

    hipLaunchKernelGGL(k_sup, dim3(200), dim3(256), 0, stream, sf, W1, b1, ws_h1);
    hipLaunchKernelGGL(k_mid2, dim3(104), dim3(256), 0, stream, ws_h1, W2, b2, Wo1, Wc1, ws_proto, ws_wb);
    hipLaunchKernelGGL(k_prep, dim3(2048), dim3(256), 0, stream, qf, ws_proto, temp,
                       ws_qbf, out_dist, out_class, out_proto);
    hipLaunchKernelGGL(k_gemm, dim3(512), dim3(512), 0, stream, ws_qbf, ws_wb,
                       bo1, Wo2, bo2, bc1, Wc2, bc2, ic, out_kp, out_conf);
}

// Round 3
// 319.115 us; speedup vs baseline: 1.0687x; 1.0687x over previous
//
#include <hip/hip_runtime.h>
#include <hip/hip_bf16.h>

#define NQ 65536
#define DIM 512
#define HID 256
#define NWAY 5
#define NKPTS 17

typedef short bf16x8 __attribute__((ext_vector_type(8)));
typedef float f32x4 __attribute__((ext_vector_type(4)));
typedef _Float16 half8 __attribute__((ext_vector_type(8)));

static __device__ __forceinline__ unsigned short f2bf(float f) {
    unsigned int x = __float_as_uint(f);
    unsigned int r = (x + 0x7fffu + ((x >> 16) & 1u)) >> 16;
    return (unsigned short)r;
}

static __device__ __forceinline__ void async16(void* l, const void* g) {
    __builtin_amdgcn_global_load_lds(
        (const __attribute__((address_space(1))) unsigned int*)g,
        (__attribute__((address_space(3))) unsigned int*)l, 16, 0, 0);
}

// ---------------- support layer 1: ws_h1 = relu(sf@W1+b1), coalesced over columns ----------
__global__ __launch_bounds__(256) void k_sup(const float* __restrict__ sf,
                                             const float* __restrict__ W1, const float* __restrict__ b1,
                                             float* __restrict__ ws_h1) {
    __shared__ float sfl[512];
    __shared__ float red[4][64];
    int bx = blockIdx.x;
    int s = bx >> 3, cb = bx & 7;
    int t = threadIdx.x;
    if (t < 128) ((float4*)sfl)[t] = ((const float4*)(sf + s * DIM))[t];
    __syncthreads();
    int c = cb * 64 + (t & 63);
    int qd = t >> 6;                 // k-quarter 0..3 (wave-uniform)
    const float* Wp = W1 + (size_t)qd * 128 * DIM + c;
    float acc = 0.0f;
    #pragma unroll 4
    for (int kk = 0; kk < 128; kk++)
        acc += sfl[qd * 128 + kk] * Wp[(size_t)kk * DIM];
    red[qd][t & 63] = acc;
    __syncthreads();
    if (t < 64) {
        float h = red[0][t] + red[1][t] + red[2][t] + red[3][t] + b1[cb * 64 + t];
        ws_h1[s * DIM + cb * 64 + t] = fmaxf(h, 0.0f);
    }
}

// ---------------- k_mid2: prototypes (mean then W2, coalesced) + [Wo1|Wc1] transpose->bf16 ----
__global__ __launch_bounds__(256) void k_mid2(const float* __restrict__ ws_h1,
                                              const float* __restrict__ W2, const float* __restrict__ b2,
                                              const float* __restrict__ Wo1, const float* __restrict__ Wc1,
                                              float* __restrict__ ws_proto, unsigned short* __restrict__ wb) {
    int bx = blockIdx.x;
    int t = threadIdx.x;
    if (bx < 40) {
        __shared__ float ml[512];
        __shared__ float red[4][64];
        int w = bx >> 3, cb = bx & 7;
        for (int i = t; i < 512; i += 256) {
            float sum = 0.0f;
            #pragma unroll
            for (int s5 = 0; s5 < 5; s5++) sum += ws_h1[(w * 5 + s5) * DIM + i];
            ml[i] = sum * 0.2f;
        }
        __syncthreads();
        int c = cb * 64 + (t & 63);
        int qd = t >> 6;
        const float* Wp = W2 + (size_t)qd * 128 * DIM + c;
        float acc = 0.0f;
        #pragma unroll 4
        for (int kk = 0; kk < 128; kk++)
            acc += ml[qd * 128 + kk] * Wp[(size_t)kk * DIM];
        red[qd][t & 63] = acc;
        __syncthreads();
        if (t < 64)
            ws_proto[w * DIM + cb * 64 + t] =
                red[0][t] + red[1][t] + red[2][t] + red[3][t] + b2[cb * 64 + t];
    } else {
        __shared__ unsigned short T[64][72];
        int tb = bx - 40;                    // 0..63
        const float* src = (tb < 32) ? Wo1 : Wc1;
        int cofs = (tb < 32) ? 0 : 256;
        int tt = tb & 31;
        int kt = tt >> 2;                    // k-tile 0..7
        int ct = tt & 3;                     // c-tile 0..3
        int i = t >> 2;                      // k row within tile 0..63
        int qd = t & 3;
        const float* rp = src + (size_t)(kt * 64 + i) * HID + ct * 64 + qd * 16;
        #pragma unroll
        for (int v = 0; v < 4; v++) {
            float4 x = *(const float4*)(rp + v * 4);
            T[qd * 16 + v * 4 + 0][i] = f2bf(x.x);
            T[qd * 16 + v * 4 + 1][i] = f2bf(x.y);
            T[qd * 16 + v * 4 + 2][i] = f2bf(x.z);
            T[qd * 16 + v * 4 + 3][i] = f2bf(x.w);
        }
        __syncthreads();
        int j = t >> 2;                      // c within tile
        int part = t & 3;
        uint4 o0 = *(const uint4*)&T[j][part * 16];
        uint4 o1 = *(const uint4*)&T[j][part * 16 + 8];
        unsigned short* dst = wb + (size_t)(cofs + ct * 64 + j) * DIM + kt * 64 + part * 16;
        *(uint4*)dst = o0;
        *(uint4*)(dst + 8) = o1;
    }
}

// ---------------- fully fused: qf(f32) -> bf16 reg-stage -> MFMA 128x512 (both heads) -------
// + f32 distance partials during A-staging (round-0 summation order) + all epilogues.
// 512 thr / 8 waves (2Mx4N, wave 64x128), BK=32, double-buffered, one barrier per K-step.
// A is read from HBM exactly ONCE; qbf workspace round-trip eliminated.
__global__ __launch_bounds__(512, 2) void k_fused2(const float* __restrict__ qf,
                                                   const unsigned short* __restrict__ wb,
                                                   const float* __restrict__ ws_proto,
                                                   const float* __restrict__ temp_p,
                                                   const float* __restrict__ bo1, const float* __restrict__ Wo2,
                                                   const float* __restrict__ bo2,
                                                   const float* __restrict__ bc1, const float* __restrict__ Wc2,
                                                   const float* __restrict__ bc2,
                                                   const float* __restrict__ ic,
                                                   float* __restrict__ out_kp, float* __restrict__ out_conf,
                                                   float* __restrict__ out_dist, float* __restrict__ out_class,
                                                   float* __restrict__ out_proto) {
    __shared__ __align__(16) char smem[94752];
    char* Abase = smem;                       // 2 x [128 rows][64B] bf16 = 16384
    char* Bbase = smem + 16384;               // 2 x [512 cols][64B] bf16 = 65536   [16384,81920)
    float* s_proto = (float*)(smem + 81920);  // 5*512 f32                          [81920,92160)
    float* pn_lds = (float*)(smem + 92160);   // 5 f32
    float* dlds = (float*)(smem + 92192);     // 128*5 f32                          [92192,94752)
    _Float16* hl = (_Float16*)smem;           // epilogue: [128][264] f16           [0,67584)
    float* redf = (float*)(smem + 67584);     // epilogue partials 4KB              [67584,71680)

    int mb = blockIdx.x;
    int t = threadIdx.x;
    int wv = t >> 6, lane = t & 63;
    int wr = wv >> 2, wc = wv & 3;
    int r = lane & 15, hq = lane >> 4;

    // prologue: stage protos to LDS; broadcast out_proto from first 85 blocks
    for (int i = t; i < NWAY * DIM; i += 512) s_proto[i] = ws_proto[i];
    if (mb < NWAY * NKPTS && t < 128) {
        f32x4 v = *(const f32x4*)(ws_proto + (mb / NKPTS) * DIM + t * 4);
        *(f32x4*)(out_proto + (size_t)mb * DIM + t * 4) = v;
    }
    float invt = 1.0f / temp_p[0];

    // B staging (global_load_lds, source pre-swizzled per rule 21)
    int srow = lane >> 2;
    int sg = (lane & 3) ^ (srow & 3);
    const unsigned short* Bg = wb + ((size_t)wv * 64 + srow) * DIM + sg * 8;

    // A per-thread ownership: row am (0..127), k-chunk akc (0..3 within 32-k window)
    int am = t >> 2, akc = t & 3;
    const float* Ag = qf + ((size_t)mb * 128 + am) * DIM + akc * 8;
    int awoff = am * 64 + ((akc ^ (am & 3)) * 16);   // swizzled byte offset in A buffer

    f32x4 acc[4][8];
    #pragma unroll
    for (int i2 = 0; i2 < 4; i2++)
        #pragma unroll
        for (int j2 = 0; j2 < 8; j2++) { f32x4 z = {0.0f, 0.0f, 0.0f, 0.0f}; acc[i2][j2] = z; }
    float ds[NWAY] = {0, 0, 0, 0, 0};
    float qq = 0.0f;

    // prologue loads: A0 -> regs, B0 -> LDS parity 0
    float4 a0 = *(const float4*)(Ag);
    float4 a1 = *(const float4*)(Ag + 4);
    #pragma unroll
    for (int i = 0; i < 4; i++)
        async16(Bbase + wv * 4096 + i * 1024, Bg + (size_t)i * 16 * DIM);

    #pragma unroll 2
    for (int it = 0; it < 16; it++) {
        int par = it & 1;
        // convert current A regs and stage to LDS (swizzled slot)
        unsigned int p0 = f2bf(a0.x) | ((unsigned int)f2bf(a0.y) << 16);
        unsigned int p1 = f2bf(a0.z) | ((unsigned int)f2bf(a0.w) << 16);
        unsigned int p2 = f2bf(a1.x) | ((unsigned int)f2bf(a1.y) << 16);
        unsigned int p3 = f2bf(a1.z) | ((unsigned int)f2bf(a1.w) << 16);
        *(uint4*)(Abase + par * 8192 + awoff) = make_uint4(p0, p1, p2, p3);
        // f32 distance partials (same summation order as the passing round-0 kernel)
        float av[8] = {a0.x, a0.y, a0.z, a0.w, a1.x, a1.y, a1.z, a1.w};
        int kb = it * 32 + akc * 8;
        #pragma unroll
        for (int w = 0; w < NWAY; w++) {
            f32x4 pv0 = *(const f32x4*)(s_proto + w * DIM + kb);
            f32x4 pv1 = *(const f32x4*)(s_proto + w * DIM + kb + 4);
            ds[w] += av[0] * pv0[0] + av[1] * pv0[1] + av[2] * pv0[2] + av[3] * pv0[3]
                   + av[4] * pv1[0] + av[5] * pv1[1] + av[6] * pv1[2] + av[7] * pv1[3];
        }
        #pragma unroll
        for (int j = 0; j < 8; j++) qq += av[j] * av[j];
        // prefetch next K-slice (loads stay in flight until the barrier drain)
        if (it < 15) {
            int ko = (it + 1) * 32;
            a0 = *(const float4*)(Ag + ko);
            a1 = *(const float4*)(Ag + ko + 4);
            #pragma unroll
            for (int i = 0; i < 4; i++)
                async16(Bbase + (par ^ 1) * 32768 + wv * 4096 + i * 1024,
                        Bg + (size_t)i * 16 * DIM + ko);
        }
        __syncthreads();   // A writes visible + B(cur) landed
        const unsigned short* Ap = (const unsigned short*)(Abase + par * 8192);
        const unsigned short* Bp = (const unsigned short*)(Bbase + par * 32768);
        int sl = (hq ^ (r & 3)) * 8;
        bf16x8 af[4], bfr[8];
        #pragma unroll
        for (int mt = 0; mt < 4; mt++)
            af[mt] = *(const bf16x8*)(Ap + (wr * 64 + mt * 16 + r) * 32 + sl);
        #pragma unroll
        for (int nt = 0; nt < 8; nt++)
            bfr[nt] = *(const bf16x8*)(Bp + (wc * 128 + nt * 16 + r) * 32 + sl);
        #pragma unroll
        for (int mt = 0; mt < 4; mt++)
            #pragma unroll
            for (int nt = 0; nt < 8; nt++)
                acc[mt][nt] = __builtin_amdgcn_mfma_f32_16x16x32_bf16(af[mt], bfr[nt], acc[mt][nt], 0, 0, 0);
    }

    __syncthreads();   // main loop drained; A/B LDS free for hl reuse

    // proto norms: wave wv<5 handles way wv
    if (wv < NWAY) {
        f32x4 a = *(const f32x4*)(s_proto + wv * DIM + lane * 8);
        f32x4 b = *(const f32x4*)(s_proto + wv * DIM + lane * 8 + 4);
        float ss = a[0]*a[0] + a[1]*a[1] + a[2]*a[2] + a[3]*a[3]
                 + b[0]*b[0] + b[1]*b[1] + b[2]*b[2] + b[3]*b[3];
        #pragma unroll
        for (int off = 32; off > 0; off >>= 1) ss += __shfl_xor(ss, off, 64);
        if (lane == 0) pn_lds[wv] = sqrtf(ss);
    }
    // offset-head h tile (cols 0..255) from waves wc<2
    if (wc < 2) {
        #pragma unroll
        for (int nt = 0; nt < 8; nt++) {
            int cl = wc * 128 + nt * 16 + r;
            float bv = bo1[cl];
            #pragma unroll
            for (int mt = 0; mt < 4; mt++)
                #pragma unroll
                for (int rg = 0; rg < 4; rg++) {
                    int ml = wr * 64 + mt * 16 + hq * 4 + rg;
                    hl[ml * 264 + cl] = (_Float16)fmaxf(acc[mt][nt][rg] + bv, 0.0f);
                }
        }
    }
    __syncthreads();   // pn_lds + hl(offset) ready

    // distance finalize: reduce over the 4 threads sharing a row, then akc==0 lanes
    #pragma unroll
    for (int off = 1; off <= 2; off <<= 1) {
        #pragma unroll
        for (int w = 0; w < NWAY; w++) ds[w] += __shfl_xor(ds[w], off, 64);
        qq += __shfl_xor(qq, off, 64);
    }
    if (akc == 0) {
        float qn = sqrtf(qq);
        float mv = 1e30f; int ami = 0;
        #pragma unroll
        for (int w = 0; w < NWAY; w++) {
            float den = fmaxf(qn * pn_lds[w], 1e-8f);
            float d = (1.0f - ds[w] / den) * invt;
            dlds[am * 5 + w] = d;
            if (d < mv) { mv = d; ami = w; }
        }
        out_class[mb * 128 + am] = (float)ami;
    }
    // offset-head dot: all 512 threads
    {
        int q = t & 127, qt = t >> 7;
        float ox = 0.0f, oy = 0.0f;
        #pragma unroll 2
        for (int j0 = 0; j0 < 64; j0 += 8) {
            half8 hv = *(const half8*)(hl + q * 264 + qt * 64 + j0);
            #pragma unroll
            for (int j = 0; j < 8; j++) {
                float2 w2 = *(const float2*)(Wo2 + (qt * 64 + j0 + j) * 2);
                float hf = (float)hv[j];
                ox += hf * w2.x;
                oy += hf * w2.y;
            }
        }
        redf[(qt * 128 + q) * 2] = ox;
        redf[(qt * 128 + q) * 2 + 1] = oy;
    }
    __syncthreads();   // redf + dlds ready

    // offset finalize (t<128) runs alongside conf h-writes (wc>=2) and dist out-writes
    if (t < 128) {
        float sx = bo2[0], sy = bo2[1];
        #pragma unroll
        for (int k2 = 0; k2 < 4; k2++) {
            sx += redf[(k2 * 128 + t) * 2];
            sy += redf[(k2 * 128 + t) * 2 + 1];
        }
        size_t Q = (size_t)mb * 128 + t;
        float2 icv = *(const float2*)(ic + Q * 2);
        float gx = icv.x / (1.0f + __expf(-sx));
        float gy = icv.y / (1.0f + __expf(-sy));
        float2 g2 = make_float2(gx, gy);
        float2* dst = (float2*)(out_kp + Q * 34);
        #pragma unroll
        for (int k2 = 0; k2 < 17; k2++) dst[k2] = g2;
    }
    if (wc >= 2) {
        #pragma unroll
        for (int nt = 0; nt < 8; nt++) {
            int cl = (wc - 2) * 128 + nt * 16 + r;
            float bv = bc1[cl];
            #pragma unroll
            for (int mt = 0; mt < 4; mt++)
                #pragma unroll
                for (int rg = 0; rg < 4; rg++) {
                    int ml = wr * 64 + mt * 16 + hq * 4 + rg;
                    hl[ml * 264 + cl] = (_Float16)fmaxf(acc[mt][nt][rg] + bv, 0.0f);
                }
        }
    }
    // dist out-write: 128 x 85 broadcast from dlds
    for (int i = t; i < 128 * NWAY * NKPTS; i += 512) {
        int q2 = i / (NWAY * NKPTS);
        int rem = i - q2 * (NWAY * NKPTS);
        out_dist[(size_t)(mb * 128 + q2) * (NWAY * NKPTS) + rem] = dlds[q2 * 5 + rem / NKPTS];
    }
    __syncthreads();   // hl(conf) ready

    {
        int q = t & 127, qt = t >> 7;
        float cs = 0.0f;
        #pragma unroll 2
        for (int j0 = 0; j0 < 64; j0 += 8) {
            half8 hv = *(const half8*)(hl + q * 264 + qt * 64 + j0);
            #pragma unroll
            for (int j = 0; j < 8; j++)
                cs += (float)hv[j] * Wc2[qt * 64 + j0 + j];
        }
        redf[qt * 128 + q] = cs;
    }
    __syncthreads();
    if (t < 128) {
        float s = bc2[0] + redf[t] + redf[128 + t] + redf[256 + t] + redf[384 + t];
        float sg2 = 1.0f / (1.0f + __expf(-s));
        size_t Q = (size_t)mb * 128 + t;
        float* dst = out_conf + Q * 17;
        #pragma unroll
        for (int k2 = 0; k2 < 17; k2++) dst[k2] = sg2;
    }
}

extern "C" void kernel_launch(void* const* d_in, const int* in_sizes, int n_in,
                              void* d_out, int out_size, void* d_ws, size_t ws_size,
                              hipStream_t stream) {
    const float* sf = (const float*)d_in[0];
    const float* qf = (const float*)d_in[2];
    const float* ic = (const float*)d_in[3];
    const float* W1 = (const float*)d_in[4];
    const float* b1 = (const float*)d_in[5];
    const float* W2 = (const float*)d_in[6];
    const float* b2 = (const float*)d_in[7];
    const float* Wo1 = (const float*)d_in[8];
    const float* bo1 = (const float*)d_in[9];
    const float* Wo2 = (const float*)d_in[10];
    const float* bo2 = (const float*)d_in[11];
    const float* Wc1 = (const float*)d_in[12];
    const float* bc1 = (const float*)d_in[13];
    const float* Wc2 = (const float*)d_in[14];
    const float* bc2 = (const float*)d_in[15];
    const float* temp = (const float*)d_in[16];

    float* out = (float*)d_out;
    float* out_kp = out;                   // 65536*17*2
    float* out_conf = out + 2228224;       // 65536*17
    float* out_dist = out + 3342336;       // 65536*5*17
    float* out_class = out + 8912896;      // 65536
    float* out_proto = out + 8978432;      // 5*17*512

    char* ws = (char*)d_ws;
    float* ws_h1 = (float*)ws;                               // 25*512 f32
    float* ws_proto = (float*)(ws + 51200);                  // 5*512 f32
    unsigned short* ws_wb = (unsigned short*)(ws + 65536);   // 512*512 bf16 (transposed [Wo1|Wc1])

    hipLaunchKernelGGL(k_sup, dim3(200), dim3(256), 0, stream, sf, W1, b1, ws_h1);
    hipLaunchKernelGGL(k_mid2, dim3(104), dim3(256), 0, stream, ws_h1, W2, b2, Wo1, Wc1, ws_proto, ws_wb);
    hipLaunchKernelGGL(k_fused2, dim3(512), dim3(512), 0, stream, qf, ws_wb, ws_proto, temp,
                       bo1, Wo2, bo2, bc1, Wc2, bc2, ic, out_kp, out_conf,
                       out_dist, out_class, out_proto);
}

// Round 4
// 318.162 us; speedup vs baseline: 1.0719x; 1.0030x over previous
//
#include <hip/hip_runtime.h>
#include <hip/hip_bf16.h>

#define NQ 65536
#define DIM 512
#define HID 256
#define NWAY 5
#define NKPTS 17

typedef short bf16x8 __attribute__((ext_vector_type(8)));
typedef float f32x4 __attribute__((ext_vector_type(4)));
typedef _Float16 half8 __attribute__((ext_vector_type(8)));

static __device__ __forceinline__ unsigned short f2bf(float f) {
    unsigned int x = __float_as_uint(f);
    unsigned int r = (x + 0x7fffu + ((x >> 16) & 1u)) >> 16;
    return (unsigned short)r;
}

static __device__ __forceinline__ void async16(void* l, const void* g) {
    __builtin_amdgcn_global_load_lds(
        (const __attribute__((address_space(1))) unsigned int*)g,
        (__attribute__((address_space(3))) unsigned int*)l, 16, 0, 0);
}

// ---------------- support layer 1: ws_h1 = relu(sf@W1+b1), coalesced over columns ----------
__global__ __launch_bounds__(256) void k_sup(const float* __restrict__ sf,
                                             const float* __restrict__ W1, const float* __restrict__ b1,
                                             float* __restrict__ ws_h1) {
    __shared__ float sfl[512];
    __shared__ float red[4][64];
    int bx = blockIdx.x;
    int s = bx >> 3, cb = bx & 7;
    int t = threadIdx.x;
    if (t < 128) ((float4*)sfl)[t] = ((const float4*)(sf + s * DIM))[t];
    __syncthreads();
    int c = cb * 64 + (t & 63);
    int qd = t >> 6;                 // k-quarter 0..3 (wave-uniform)
    const float* Wp = W1 + (size_t)qd * 128 * DIM + c;
    float acc = 0.0f;
    #pragma unroll 4
    for (int kk = 0; kk < 128; kk++)
        acc += sfl[qd * 128 + kk] * Wp[(size_t)kk * DIM];
    red[qd][t & 63] = acc;
    __syncthreads();
    if (t < 64) {
        float h = red[0][t] + red[1][t] + red[2][t] + red[3][t] + b1[cb * 64 + t];
        ws_h1[s * DIM + cb * 64 + t] = fmaxf(h, 0.0f);
    }
}

// ---------------- k_mid2: prototypes (mean then W2, coalesced) + [Wo1|Wc1] transpose->bf16 ----
__global__ __launch_bounds__(256) void k_mid2(const float* __restrict__ ws_h1,
                                              const float* __restrict__ W2, const float* __restrict__ b2,
                                              const float* __restrict__ Wo1, const float* __restrict__ Wc1,
                                              float* __restrict__ ws_proto, unsigned short* __restrict__ wb) {
    int bx = blockIdx.x;
    int t = threadIdx.x;
    if (bx < 40) {
        __shared__ float ml[512];
        __shared__ float red[4][64];
        int w = bx >> 3, cb = bx & 7;
        for (int i = t; i < 512; i += 256) {
            float sum = 0.0f;
            #pragma unroll
            for (int s5 = 0; s5 < 5; s5++) sum += ws_h1[(w * 5 + s5) * DIM + i];
            ml[i] = sum * 0.2f;
        }
        __syncthreads();
        int c = cb * 64 + (t & 63);
        int qd = t >> 6;
        const float* Wp = W2 + (size_t)qd * 128 * DIM + c;
        float acc = 0.0f;
        #pragma unroll 4
        for (int kk = 0; kk < 128; kk++)
            acc += ml[qd * 128 + kk] * Wp[(size_t)kk * DIM];
        red[qd][t & 63] = acc;
        __syncthreads();
        if (t < 64)
            ws_proto[w * DIM + cb * 64 + t] =
                red[0][t] + red[1][t] + red[2][t] + red[3][t] + b2[cb * 64 + t];
    } else {
        __shared__ unsigned short T[64][72];
        int tb = bx - 40;                    // 0..63
        const float* src = (tb < 32) ? Wo1 : Wc1;
        int cofs = (tb < 32) ? 0 : 256;
        int tt = tb & 31;
        int kt = tt >> 2;                    // k-tile 0..7
        int ct = tt & 3;                     // c-tile 0..3
        int i = t >> 2;                      // k row within tile 0..63
        int qd = t & 3;
        const float* rp = src + (size_t)(kt * 64 + i) * HID + ct * 64 + qd * 16;
        #pragma unroll
        for (int v = 0; v < 4; v++) {
            float4 x = *(const float4*)(rp + v * 4);
            T[qd * 16 + v * 4 + 0][i] = f2bf(x.x);
            T[qd * 16 + v * 4 + 1][i] = f2bf(x.y);
            T[qd * 16 + v * 4 + 2][i] = f2bf(x.z);
            T[qd * 16 + v * 4 + 3][i] = f2bf(x.w);
        }
        __syncthreads();
        int j = t >> 2;                      // c within tile
        int part = t & 3;
        uint4 o0 = *(const uint4*)&T[j][part * 16];
        uint4 o1 = *(const uint4*)&T[j][part * 16 + 8];
        unsigned short* dst = wb + (size_t)(cofs + ct * 64 + j) * DIM + kt * 64 + part * 16;
        *(uint4*)dst = o0;
        *(uint4*)(dst + 8) = o1;
    }
}

// ---------------- fused MFMA GEMM, counted-vmcnt pipeline (T3+T4) -----------------------
// 128x512 tile, BK=32, 16 K-steps. A: f32->bf16 reg-staged, prefetch distance 2 (regs).
// B: global_load_lds, TRIPLE-buffered LDS, prefetch distance 2. Barriers are raw s_barrier
// with counted vmcnt — prefetches stay in flight across barriers (no vmcnt(0) drain).
// f32 distance partials ride the A-staging regs (identical summation order to prior rounds).
__global__ __launch_bounds__(512) void k_fused3(const float* __restrict__ qf,
                                                const unsigned short* __restrict__ wb,
                                                const float* __restrict__ ws_proto,
                                                const float* __restrict__ temp_p,
                                                const float* __restrict__ bo1, const float* __restrict__ Wo2,
                                                const float* __restrict__ bo2,
                                                const float* __restrict__ bc1, const float* __restrict__ Wc2,
                                                const float* __restrict__ bc2,
                                                const float* __restrict__ ic,
                                                float* __restrict__ out_kp, float* __restrict__ out_conf,
                                                float* __restrict__ out_dist, float* __restrict__ out_class,
                                                float* __restrict__ out_proto) {
    __shared__ __align__(16) char smem[127520];
    char* Abase = smem;                       // 2 x [128 rows][64B] = 16384         [0,16384)
    char* Bbase = smem + 16384;               // 3 x [512 cols][64B] = 98304         [16384,114688)
    float* s_proto = (float*)(smem + 114688); // 5*512 f32                           [114688,124928)
    float* dlds = (float*)(smem + 124928);    // 128*5 f32                           [124928,127488)
    float* pn_lds = (float*)(smem + 127488);  // 5 f32
    _Float16* hl = (_Float16*)smem;           // epilogue: [128][264] f16            [0,67584)
    float* redf = (float*)(smem + 67584);     // epilogue partials 4KB               [67584,71680)

    int mb = blockIdx.x;
    int t = threadIdx.x;
    int wv = t >> 6, lane = t & 63;
    int wr = wv >> 2, wc = wv & 3;
    int r = lane & 15, hq = lane >> 4;

    // ---- prologue: proto -> LDS, out_proto broadcast, then full drain ----
    for (int i = t; i < NWAY * DIM; i += 512) s_proto[i] = ws_proto[i];
    if (mb < NWAY * NKPTS && t < 128) {
        f32x4 v = *(const f32x4*)(ws_proto + (mb / NKPTS) * DIM + t * 4);
        *(f32x4*)(out_proto + (size_t)mb * DIM + t * 4) = v;
    }
    float invt = 1.0f / temp_p[0];
    __syncthreads();   // s_proto visible; vmcnt drained to 0 uniformly across waves

    // proto norms now (f32, from LDS)
    if (wv < NWAY) {
        f32x4 a = *(const f32x4*)(s_proto + wv * DIM + lane * 8);
        f32x4 b = *(const f32x4*)(s_proto + wv * DIM + lane * 8 + 4);
        float ss = a[0]*a[0] + a[1]*a[1] + a[2]*a[2] + a[3]*a[3]
                 + b[0]*b[0] + b[1]*b[1] + b[2]*b[2] + b[3]*b[3];
        #pragma unroll
        for (int off = 32; off > 0; off >>= 1) ss += __shfl_xor(ss, off, 64);
        if (lane == 0) pn_lds[wv] = sqrtf(ss);
    }

    // staging addresses
    int am = t >> 2, akc = t & 3;                         // A: row, k-chunk
    const float* Ag = qf + ((size_t)mb * 128 + am) * DIM + akc * 8;
    int awoff = am * 64 + ((akc ^ (am & 3)) * 16);        // swizzled A byte offset
    int srow = lane >> 2;
    int sg = (lane & 3) ^ (srow & 3);                     // pre-swizzled B source slot
    const unsigned short* Bg = wb + ((size_t)wv * 64 + srow) * DIM + sg * 8;

    f32x4 acc[4][8];
    #pragma unroll
    for (int i2 = 0; i2 < 4; i2++)
        #pragma unroll
        for (int j2 = 0; j2 < 8; j2++) { f32x4 z = {0.0f, 0.0f, 0.0f, 0.0f}; acc[i2][j2] = z; }
    float ds[NWAY] = {0, 0, 0, 0, 0};
    float qq = 0.0f;

    // ---- prologue issues: a(0), a(1) to regs; B(0)->p0, B(1)->p1 (8 vmem/wave total) ----
    float4 aW0 = *(const float4*)(Ag);
    float4 aW1 = *(const float4*)(Ag + 4);
    float4 aN0 = *(const float4*)(Ag + 32);
    float4 aN1 = *(const float4*)(Ag + 36);
    #pragma unroll
    for (int i = 0; i < 4; i++)
        async16(Bbase + (wv * 4 + i) * 1024, Bg + (size_t)i * 16 * DIM);
    #pragma unroll
    for (int i = 0; i < 4; i++)
        async16(Bbase + 32768 + (wv * 4 + i) * 1024, Bg + (size_t)i * 16 * DIM + 32);

    // stage A(0) + dist window 0 (consumes a(0); compiler inserts the vmcnt wait)
    {
        unsigned int p0 = f2bf(aW0.x) | ((unsigned int)f2bf(aW0.y) << 16);
        unsigned int p1 = f2bf(aW0.z) | ((unsigned int)f2bf(aW0.w) << 16);
        unsigned int p2 = f2bf(aW1.x) | ((unsigned int)f2bf(aW1.y) << 16);
        unsigned int p3 = f2bf(aW1.z) | ((unsigned int)f2bf(aW1.w) << 16);
        *(uint4*)(Abase + awoff) = make_uint4(p0, p1, p2, p3);
        float av[8] = {aW0.x, aW0.y, aW0.z, aW0.w, aW1.x, aW1.y, aW1.z, aW1.w};
        int kb = akc * 8;
        #pragma unroll
        for (int w = 0; w < NWAY; w++) {
            f32x4 pv0 = *(const f32x4*)(s_proto + w * DIM + kb);
            f32x4 pv1 = *(const f32x4*)(s_proto + w * DIM + kb + 4);
            ds[w] += av[0] * pv0[0] + av[1] * pv0[1] + av[2] * pv0[2] + av[3] * pv0[3]
                   + av[4] * pv1[0] + av[5] * pv1[1] + av[6] * pv1[2] + av[7] * pv1[3];
        }
        #pragma unroll
        for (int j = 0; j < 8; j++) qq += av[j] * av[j];
    }
    aW0 = aN0; aW1 = aN1;   // aW := a(1)

    // barrier: force B(0) landed (allow B(1)'s 4 loads in flight)
    asm volatile("s_waitcnt lgkmcnt(0) vmcnt(4)" ::: "memory");
    __builtin_amdgcn_s_barrier();
    __builtin_amdgcn_sched_barrier(0);

    // ---- main loop: compute K-window it; prefetch it+2; stage A(it+1) ----
    #pragma unroll 2
    for (int it = 0; it < 16; it++) {
        int apar = it & 1;
        int bpar = it % 3;
        float4 aL0, aL1;
        if (it < 14) {
            int ko = (it + 2) * 32;
            aL0 = *(const float4*)(Ag + ko);
            aL1 = *(const float4*)(Ag + ko + 4);
            int bp2 = (it + 2) % 3;
            #pragma unroll
            for (int i = 0; i < 4; i++)
                async16(Bbase + bp2 * 32768 + (wv * 4 + i) * 1024,
                        Bg + (size_t)i * 16 * DIM + ko);
        }
        if (it < 15) {
            // stage A(it+1) into parity apar^1 + dist window it+1 (from aW = a(it+1))
            unsigned int p0 = f2bf(aW0.x) | ((unsigned int)f2bf(aW0.y) << 16);
            unsigned int p1 = f2bf(aW0.z) | ((unsigned int)f2bf(aW0.w) << 16);
            unsigned int p2 = f2bf(aW1.x) | ((unsigned int)f2bf(aW1.y) << 16);
            unsigned int p3 = f2bf(aW1.z) | ((unsigned int)f2bf(aW1.w) << 16);
            *(uint4*)(Abase + (apar ^ 1) * 8192 + awoff) = make_uint4(p0, p1, p2, p3);
            float av[8] = {aW0.x, aW0.y, aW0.z, aW0.w, aW1.x, aW1.y, aW1.z, aW1.w};
            int kb = (it + 1) * 32 + akc * 8;
            #pragma unroll
            for (int w = 0; w < NWAY; w++) {
                f32x4 pv0 = *(const f32x4*)(s_proto + w * DIM + kb);
                f32x4 pv1 = *(const f32x4*)(s_proto + w * DIM + kb + 4);
                ds[w] += av[0] * pv0[0] + av[1] * pv0[1] + av[2] * pv0[2] + av[3] * pv0[3]
                       + av[4] * pv1[0] + av[5] * pv1[1] + av[6] * pv1[2] + av[7] * pv1[3];
            }
            #pragma unroll
            for (int j = 0; j < 8; j++) qq += av[j] * av[j];
        }
        // fragments + MFMA on A(it)/B(it)
        const unsigned short* Ap = (const unsigned short*)(Abase + apar * 8192);
        const unsigned short* Bp = (const unsigned short*)(Bbase + bpar * 32768);
        int sl = (hq ^ (r & 3)) * 8;
        bf16x8 af[4], bfr[8];
        #pragma unroll
        for (int mt = 0; mt < 4; mt++)
            af[mt] = *(const bf16x8*)(Ap + (wr * 64 + mt * 16 + r) * 32 + sl);
        #pragma unroll
        for (int nt = 0; nt < 8; nt++)
            bfr[nt] = *(const bf16x8*)(Bp + (wc * 128 + nt * 16 + r) * 32 + sl);
        #pragma unroll
        for (int mt = 0; mt < 4; mt++)
            #pragma unroll
            for (int nt = 0; nt < 8; nt++)
                acc[mt][nt] = __builtin_amdgcn_mfma_f32_16x16x32_bf16(af[mt], bfr[nt], acc[mt][nt], 0, 0, 0);
        if (it < 15) {
            // counted barrier: require A(it+1) writes + B(it+1) landed; keep 6 newest in flight
            if (it < 14) { asm volatile("s_waitcnt lgkmcnt(0) vmcnt(6)" ::: "memory"); }
            else         { asm volatile("s_waitcnt lgkmcnt(0) vmcnt(0)" ::: "memory"); }
            __builtin_amdgcn_s_barrier();
            __builtin_amdgcn_sched_barrier(0);
        }
        if (it < 14) { aW0 = aL0; aW1 = aL1; }
    }
    __syncthreads();   // loop fully drained; A/B LDS regions free for hl reuse

    // ---- offset-head h tile (cols 0..255) from waves wc<2 ----
    if (wc < 2) {
        #pragma unroll
        for (int nt = 0; nt < 8; nt++) {
            int cl = wc * 128 + nt * 16 + r;
            float bv = bo1[cl];
            #pragma unroll
            for (int mt = 0; mt < 4; mt++)
                #pragma unroll
                for (int rg = 0; rg < 4; rg++) {
                    int ml = wr * 64 + mt * 16 + hq * 4 + rg;
                    hl[ml * 264 + cl] = (_Float16)fmaxf(acc[mt][nt][rg] + bv, 0.0f);
                }
        }
    }
    __syncthreads();   // hl(offset) ready

    // distance finalize: reduce over the 4 threads sharing a row, then akc==0 lanes
    #pragma unroll
    for (int off = 1; off <= 2; off <<= 1) {
        #pragma unroll
        for (int w = 0; w < NWAY; w++) ds[w] += __shfl_xor(ds[w], off, 64);
        qq += __shfl_xor(qq, off, 64);
    }
    if (akc == 0) {
        float qn = sqrtf(qq);
        float mv = 1e30f; int ami = 0;
        #pragma unroll
        for (int w = 0; w < NWAY; w++) {
            float den = fmaxf(qn * pn_lds[w], 1e-8f);
            float d = (1.0f - ds[w] / den) * invt;
            dlds[am * 5 + w] = d;
            if (d < mv) { mv = d; ami = w; }
        }
        out_class[mb * 128 + am] = (float)ami;
    }
    // offset-head dot: all 512 threads
    {
        int q = t & 127, qt = t >> 7;
        float ox = 0.0f, oy = 0.0f;
        #pragma unroll 2
        for (int j0 = 0; j0 < 64; j0 += 8) {
            half8 hv = *(const half8*)(hl + q * 264 + qt * 64 + j0);
            #pragma unroll
            for (int j = 0; j < 8; j++) {
                float2 w2 = *(const float2*)(Wo2 + (qt * 64 + j0 + j) * 2);
                float hf = (float)hv[j];
                ox += hf * w2.x;
                oy += hf * w2.y;
            }
        }
        redf[(qt * 128 + q) * 2] = ox;
        redf[(qt * 128 + q) * 2 + 1] = oy;
    }
    __syncthreads();   // redf + dlds ready

    // offset finalize (t<128) alongside conf h-writes (wc>=2) and dist out-writes
    if (t < 128) {
        float sx = bo2[0], sy = bo2[1];
        #pragma unroll
        for (int k2 = 0; k2 < 4; k2++) {
            sx += redf[(k2 * 128 + t) * 2];
            sy += redf[(k2 * 128 + t) * 2 + 1];
        }
        size_t Q = (size_t)mb * 128 + t;
        float2 icv = *(const float2*)(ic + Q * 2);
        float gx = icv.x / (1.0f + __expf(-sx));
        float gy = icv.y / (1.0f + __expf(-sy));
        float2 g2 = make_float2(gx, gy);
        float2* dst = (float2*)(out_kp + Q * 34);
        #pragma unroll
        for (int k2 = 0; k2 < 17; k2++) dst[k2] = g2;
    }
    if (wc >= 2) {
        #pragma unroll
        for (int nt = 0; nt < 8; nt++) {
            int cl = (wc - 2) * 128 + nt * 16 + r;
            float bv = bc1[cl];
            #pragma unroll
            for (int mt = 0; mt < 4; mt++)
                #pragma unroll
                for (int rg = 0; rg < 4; rg++) {
                    int ml = wr * 64 + mt * 16 + hq * 4 + rg;
                    hl[ml * 264 + cl] = (_Float16)fmaxf(acc[mt][nt][rg] + bv, 0.0f);
                }
        }
    }
    // dist out-write: 128 x 85 broadcast from dlds
    for (int i = t; i < 128 * NWAY * NKPTS; i += 512) {
        int q2 = i / (NWAY * NKPTS);
        int rem = i - q2 * (NWAY * NKPTS);
        out_dist[(size_t)(mb * 128 + q2) * (NWAY * NKPTS) + rem] = dlds[q2 * 5 + rem / NKPTS];
    }
    __syncthreads();   // hl(conf) ready

    {
        int q = t & 127, qt = t >> 7;
        float cs = 0.0f;
        #pragma unroll 2
        for (int j0 = 0; j0 < 64; j0 += 8) {
            half8 hv = *(const half8*)(hl + q * 264 + qt * 64 + j0);
            #pragma unroll
            for (int j = 0; j < 8; j++)
                cs += (float)hv[j] * Wc2[qt * 64 + j0 + j];
        }
        redf[qt * 128 + q] = cs;
    }
    __syncthreads();
    if (t < 128) {
        float s = bc2[0] + redf[t] + redf[128 + t] + redf[256 + t] + redf[384 + t];
        float sg2 = 1.0f / (1.0f + __expf(-s));
        size_t Q = (size_t)mb * 128 + t;
        float* dst = out_conf + Q * 17;
        #pragma unroll
        for (int k2 = 0; k2 < 17; k2++) dst[k2] = sg2;
    }
}

extern "C" void kernel_launch(void* const* d_in, const int* in_sizes, int n_in,
                              void* d_out, int out_size, void* d_ws, size_t ws_size,
                              hipStream_t stream) {
    const float* sf = (const float*)d_in[0];
    const float* qf = (const float*)d_in[2];
    const float* ic = (const float*)d_in[3];
    const float* W1 = (const float*)d_in[4];
    const float* b1 = (const float*)d_in[5];
    const float* W2 = (const float*)d_in[6];
    const float* b2 = (const float*)d_in[7];
    const float* Wo1 = (const float*)d_in[8];
    const float* bo1 = (const float*)d_in[9];
    const float* Wo2 = (const float*)d_in[10];
    const float* bo2 = (const float*)d_in[11];
    const float* Wc1 = (const float*)d_in[12];
    const float* bc1 = (const float*)d_in[13];
    const float* Wc2 = (const float*)d_in[14];
    const float* bc2 = (const float*)d_in[15];
    const float* temp = (const float*)d_in[16];

    float* out = (float*)d_out;
    float* out_kp = out;                   // 65536*17*2
    float* out_conf = out + 2228224;       // 65536*17
    float* out_dist = out + 3342336;       // 65536*5*17
    float* out_class = out + 8912896;      // 65536
    float* out_proto = out + 8978432;      // 5*17*512

    char* ws = (char*)d_ws;
    float* ws_h1 = (float*)ws;                               // 25*512 f32
    float* ws_proto = (float*)(ws + 51200);                  // 5*512 f32
    unsigned short* ws_wb = (unsigned short*)(ws + 65536);   // 512*512 bf16 (transposed [Wo1|Wc1])

    hipLaunchKernelGGL(k_sup, dim3(200), dim3(256), 0, stream, sf, W1, b1, ws_h1);
    hipLaunchKernelGGL(k_mid2, dim3(104), dim3(256), 0, stream, ws_h1, W2, b2, Wo1, Wc1, ws_proto, ws_wb);
    hipLaunchKernelGGL(k_fused3, dim3(512), dim3(512), 0, stream, qf, ws_wb, ws_proto, temp,
                       bo1, Wo2, bo2, bc1, Wc2, bc2, ic, out_kp, out_conf,
                       out_dist, out_class, out_proto);
}